// Round 14
// baseline (61.159 us; speedup 1.0000x reference)
//
#include <hip/hip_runtime.h>

// Problem constants (match reference setup_inputs)
#define B_ 8
#define T_ 1024
#define S_ 4096
#define H_ 256

#define STRIP 64           // tokens per producer strip
#define CHUNK 128          // tag rows per early-exit check (4 waves x 32 rows)
#define NSTRIP (S_ / STRIP)          // 64 strips per batch
#define MAGICF 0x5F3759DFu           // done-flag value (!= 0xAAAAAAAA poison)

// One kernel, 512 blocks x 256 threads (2 blocks/CU -> co-resident by
// capacity; no grid.sync). Phase 1: block produces strip sid=blockIdx.x
// (R12's proven early-exit colmax + [Lmin,Lmax] range), publishes via
// __threadfence + atomicExch flag. Phase 2: block consumes 16 output rows of
// batch b2=blockIdx.x*16/1024; each wave polls its batch's 64 per-strip flags
// (lane=strip, s_sleep backoff), then does the range-filtered gather.
// Cross-XCD safety: L/range/flag consumer reads use agent-scope atomic loads.
__global__ void __launch_bounds__(256) fused_flag_kernel(
    const float* __restrict__ inputs,
    const float* __restrict__ ttt,
    const float* __restrict__ seq_emb,
    float* __restrict__ out,
    int* __restrict__ L,
    int2* __restrict__ range,
    unsigned int* __restrict__ flag) {

    __shared__ unsigned long long wmask[2][4];
    __shared__ int red[4][STRIP];
    const int w    = threadIdx.x >> 6;
    const int lane = threadIdx.x & 63;

    // ---------------- Phase 1: produce strip sid = blockIdx.x ----------------
    {
        const int strippos = blockIdx.x >> 3;   // expensive (low s0) first
        const int b  = blockIdx.x & 7;
        const int s0 = strippos * STRIP;
        const float* colbase = ttt + (size_t)b * T_ * S_ + s0 + lane;

        int best = -1;
        int par = 0;
        float v[32], vn[32];

        {   // prologue: top chunk, wave w's 32-row slice
            const float* p = colbase + (size_t)(T_ - CHUNK + w * 32) * S_;
#pragma unroll
            for (int j = 0; j < 32; ++j) v[j] = p[(size_t)j * S_];
        }

        for (int thi = T_; thi > 0; thi -= CHUNK) {
            const int t0 = thi - CHUNK + w * 32;
            if (thi > CHUNK) {                  // prefetch next chunk
                const float* pn = colbase + (size_t)(t0 - CHUNK) * S_;
#pragma unroll
                for (int j = 0; j < 32; ++j) vn[j] = pn[(size_t)j * S_];
            }
            int lm = -1;
#pragma unroll
            for (int j = 0; j < 32; ++j)
                if (v[j] > 0.0f) lm = t0 + j;   // ascending -> in-chunk max
            best = max(best, lm);

            wmask[par][w] = __ballot(best >= 0);
            __syncthreads();
            unsigned long long all = wmask[par][0] | wmask[par][1]
                                   | wmask[par][2] | wmask[par][3];
            if (all == ~0ull) break;
            par ^= 1;
#pragma unroll
            for (int j = 0; j < 32; ++j) v[j] = vn[j];
        }

        red[w][lane] = best;
        __syncthreads();
        if (threadIdx.x < STRIP) {              // wave 0 finalizes
            const int tid = threadIdx.x;
            int m = max(max(red[0][tid], red[1][tid]),
                        max(red[2][tid], red[3][tid]));
            L[b * S_ + s0 + tid] = m;
            int mn = (m < 0) ? 0x7fffffff : m;
            int mx = m;
#pragma unroll
            for (int k = 32; k >= 1; k >>= 1) {
                mn = min(mn, __shfl_xor(mn, k));
                mx = max(mx, __shfl_xor(mx, k));
            }
            if (tid == 0) {
                int2 rg = {mn, mx};             // empty strip: (INT_MAX,-1)
                range[b * NSTRIP + strippos] = rg;
                __threadfence();                // release L/range device-wide
                atomicExch(&flag[blockIdx.x], MAGICF);
            }
        }
    }

    // ---------------- Phase 2: consume 16 rows of batch b2 -------------------
    {
        const int bt_base = blockIdx.x * 16;    // 512 blocks x 16 rows = 8192
        const int b2 = bt_base >> 10;

        // wait for all 64 strips of batch b2 (lane = strip index)
        {
            const int sid = lane * 8 + b2;
            while (__hip_atomic_load(&flag[sid], __ATOMIC_ACQUIRE,
                                     __HIP_MEMORY_SCOPE_AGENT) != MAGICF)
                __builtin_amdgcn_s_sleep(8);
        }

        // per-lane strip range (agent load dodges stale XCD-local cache)
        int2 rg;
        {
            unsigned long long rr = __hip_atomic_load(
                (const unsigned long long*)&range[b2 * NSTRIP + lane],
                __ATOMIC_RELAXED, __HIP_MEMORY_SCOPE_AGENT);
            rg.x = (int)(unsigned int)(rr & 0xffffffffull);
            rg.y = (int)(unsigned int)(rr >> 32);
        }

        const float4* in4 = reinterpret_cast<const float4*>(inputs);

        for (int r = 0; r < 4; ++r) {           // wave w owns rows w*4 .. w*4+3
            const int bt = bt_base + w * 4 + r;
            const int t = bt & (T_ - 1);

            unsigned long long smask = __ballot(rg.x <= t && t <= rg.y);
            float4 acc = {0.0f, 0.0f, 0.0f, 0.0f};
            int c = 0;

            while (smask) {                     // wave-uniform candidate strips
                int strip = __ffsll(smask) - 1; smask &= smask - 1;
                int Lv = __hip_atomic_load(&L[b2 * S_ + strip * STRIP + lane],
                                           __ATOMIC_RELAXED,
                                           __HIP_MEMORY_SCOPE_AGENT);
                unsigned long long bm = __ballot(Lv == t);
                while (bm) {
                    int l = __ffsll(bm) - 1; bm &= bm - 1;
                    int s = strip * STRIP + l;
                    float4 rr4 = in4[(size_t)(b2 * S_ + s) * (H_ / 4) + lane];
                    acc.x += rr4.x; acc.y += rr4.y;
                    acc.z += rr4.z; acc.w += rr4.w; c++;
                }
            }

            float inv = (c > 0) ? (1.0f / (float)c) : 0.0f;  // empty -> emb
            float4 e = reinterpret_cast<const float4*>(seq_emb)[t * (H_ / 4) + lane];
            float4 o;
            o.x = acc.x * inv + e.x;
            o.y = acc.y * inv + e.y;
            o.z = acc.z * inv + e.z;
            o.w = acc.w * inv + e.w;
            reinterpret_cast<float4*>(out)[(size_t)bt * (H_ / 4) + lane] = o;
        }
    }
}

extern "C" void kernel_launch(void* const* d_in, const int* in_sizes, int n_in,
                              void* d_out, int out_size, void* d_ws, size_t ws_size,
                              hipStream_t stream) {
    const float* inputs  = (const float*)d_in[0];   // [B,S,H]
    const float* ttt     = (const float*)d_in[1];   // [B,T,S]
    const float* seq_emb = (const float*)d_in[2];   // [T,H]
    float* out = (float*)d_out;                     // [B,T,H]

    int* L = (int*)d_ws;                            // B*S ints      (128 KiB)
    int2* range = (int2*)(L + B_ * S_);             // 512 int2      (4 KiB)
    unsigned int* flag = (unsigned int*)(range + B_ * NSTRIP);  // 512 u32 (2 KiB)

    fused_flag_kernel<<<B_ * NSTRIP, 256, 0, stream>>>(
        inputs, ttt, seq_emb, out, L, range, flag);
}

// Round 15
// 28.299 us; speedup vs baseline: 2.1612x; 2.1612x over previous
//
#include <hip/hip_runtime.h>

// Problem constants (match reference setup_inputs)
#define B_ 8
#define T_ 1024
#define S_ 4096
#define H_ 256

#define STRIP 64           // tokens per K1 block
#define CHUNK 128          // tag rows per early-exit check (4 waves x 32 rows)

// K1: top-down early-exit column-max, software-pipelined (R11 form), plus a
// free epilogue: per-strip [Lmin, Lmax] over found tokens (12 shuffles + one
// int2 store). range[] lets K2 skip whole strips.
// NOTE (session journal): K1 lands at ~20-22us under ALL tested structures
// (full-scan R6, early-exit R7, cost-paired R10, pipelined R11, reg-dbuf R13);
// fusion via grid.sync (R5) or flag-handoff (R14) regresses >=2x. This is the
// practical floor for the phase; do not re-attempt scheduling variants.
__global__ void __launch_bounds__(256) colmax_pipe_kernel(const float* __restrict__ ttt,
                                                          int* __restrict__ L,
                                                          int2* __restrict__ range) {
    __shared__ unsigned long long wmask[2][4];
    __shared__ int red[4][STRIP];
    const int strippos = blockIdx.x >> 3;   // low s0 (expensive) first
    const int b  = blockIdx.x & 7;
    const int s0 = strippos * STRIP;
    const int w    = threadIdx.x >> 6;
    const int lane = threadIdx.x & 63;

    const float* colbase = ttt + (size_t)b * T_ * S_ + s0 + lane;

    int best = -1;
    int par = 0;
    float v[32], vn[32];

    // prologue: load top chunk (rows T-CHUNK .. T-1), wave w's 32-row slice
    {
        const float* p = colbase + (size_t)(T_ - CHUNK + w * 32) * S_;
#pragma unroll
        for (int j = 0; j < 32; ++j)
            v[j] = p[(size_t)j * S_];
    }

    for (int thi = T_; thi > 0; thi -= CHUNK) {
        const int t0 = thi - CHUNK + w * 32;
        // prefetch next chunk while current is processed
        if (thi > CHUNK) {
            const float* pn = colbase + (size_t)(t0 - CHUNK) * S_;
#pragma unroll
            for (int j = 0; j < 32; ++j)
                vn[j] = pn[(size_t)j * S_];
        }
        // process current chunk (ascending j -> in-chunk max; chunks visited
        // top-down so first-found is the global max for this lane)
        int lm = -1;
#pragma unroll
        for (int j = 0; j < 32; ++j)
            if (v[j] > 0.0f) lm = t0 + j;
        best = max(best, lm);

        wmask[par][w] = __ballot(best >= 0);    // all lanes write same value
        __syncthreads();
        unsigned long long all = wmask[par][0] | wmask[par][1]
                               | wmask[par][2] | wmask[par][3];
        if (all == ~0ull) break;                // uniform across block
        par ^= 1;
#pragma unroll
        for (int j = 0; j < 32; ++j)
            v[j] = vn[j];
    }

    // epilogue: cross-wave max-combine -> L, plus strip [Lmin,Lmax] -> range
    red[w][lane] = best;
    __syncthreads();
    if (threadIdx.x < STRIP) {                  // exactly wave 0, all 64 lanes
        const int tid = threadIdx.x;
        int m = max(max(red[0][tid], red[1][tid]),
                    max(red[2][tid], red[3][tid]));
        L[b * S_ + s0 + tid] = m;
        int mn = (m < 0) ? 0x7fffffff : m;      // not-found -> +INF for min
        int mx = m;                             // not-found -1 never wins max
#pragma unroll
        for (int k = 32; k >= 1; k >>= 1) {
            mn = min(mn, __shfl_xor(mn, k));
            mx = max(mx, __shfl_xor(mx, k));
        }
        if (tid == 0) {
            int2 rg = {mn, mx};                 // empty strip -> (INT_MAX,-1): no t matches
            range[b * (S_ / STRIP) + strippos] = rg;
        }
    }
}

// K2: range-filtered gather + mean + seq_emb. One wave per (b,t) output row.
// Lane = strip: one ballot over per-strip [Lmin,Lmax] selects candidate strips
// (L[b,s]==t implies t is within strip(s)'s range). Only those strips' 64 L
// values are read (coalesced 256B); matches gather coalesced float4 input
// rows. Ascending strip then ascending bit -> ascending s (absmax-0 order).
__global__ void __launch_bounds__(256) gather_range_kernel(const float* __restrict__ inputs,
                                                           const int* __restrict__ L,
                                                           const int2* __restrict__ range,
                                                           const float* __restrict__ seq_emb,
                                                           float* __restrict__ out) {
    const int wid  = threadIdx.x >> 6;
    const int lane = threadIdx.x & 63;
    const int bt = blockIdx.x * 4 + wid;         // (b*T + t), 4 waves per block
    const int b = bt >> 10;
    const int t = bt & (T_ - 1);

    const float4* in4 = reinterpret_cast<const float4*>(inputs);

    int2 rg = range[b * (S_ / STRIP) + lane];    // lane = strip id (64 strips)
    unsigned long long smask = __ballot(rg.x <= t && t <= rg.y);

    float4 acc = {0.0f, 0.0f, 0.0f, 0.0f};
    int c = 0;

    while (smask) {                              // wave-uniform loop
        int strip = __ffsll(smask) - 1; smask &= smask - 1;
        int Lv = L[b * S_ + strip * STRIP + lane];
        unsigned long long bm = __ballot(Lv == t);
        while (bm) {
            int l = __ffsll(bm) - 1; bm &= bm - 1;
            int s = strip * STRIP + l;
            float4 r = in4[(size_t)(b * S_ + s) * (H_ / 4) + lane];
            acc.x += r.x; acc.y += r.y; acc.z += r.z; acc.w += r.w; c++;
        }
    }

    float inv = (c > 0) ? (1.0f / (float)c) : 0.0f;   // empty row -> just emb
    float4 e = reinterpret_cast<const float4*>(seq_emb)[t * (H_ / 4) + lane];
    float4 o;
    o.x = acc.x * inv + e.x;
    o.y = acc.y * inv + e.y;
    o.z = acc.z * inv + e.z;
    o.w = acc.w * inv + e.w;
    reinterpret_cast<float4*>(out)[(size_t)bt * (H_ / 4) + lane] = o;
}

extern "C" void kernel_launch(void* const* d_in, const int* in_sizes, int n_in,
                              void* d_out, int out_size, void* d_ws, size_t ws_size,
                              hipStream_t stream) {
    const float* inputs  = (const float*)d_in[0];   // [B,S,H]
    const float* ttt     = (const float*)d_in[1];   // [B,T,S]
    const float* seq_emb = (const float*)d_in[2];   // [T,H]
    float* out = (float*)d_out;                     // [B,T,H]

    int* L = (int*)d_ws;                            // B*S ints (128 KiB)
    int2* range = (int2*)(L + B_ * S_);             // 512 int2 (4 KiB)

    // K1: software-pipelined early-exit column-max + strip ranges
    colmax_pipe_kernel<<<B_ * (S_ / STRIP), 256, 0, stream>>>(ttt, L, range);

    // K2: range-filtered gather + mean + emb (B*T/4 blocks, 1 wave per row)
    gather_range_kernel<<<B_ * T_ / 4, 256, 0, stream>>>(inputs, L, range, seq_emb, out);
}